// Round 2
// baseline (235.775 us; speedup 1.0000x reference)
//
#include <hip/hip_runtime.h>

typedef __bf16 bf16x8 __attribute__((ext_vector_type(8)));
typedef float f32x4 __attribute__((ext_vector_type(4)));
typedef unsigned int u32x4 __attribute__((ext_vector_type(4)));
typedef unsigned int u32x2 __attribute__((ext_vector_type(2)));
typedef u32x4 u32x4a __attribute__((may_alias));
typedef u32x2 u32x2a __attribute__((may_alias));
typedef f32x4 f32x4a __attribute__((may_alias));
typedef unsigned int u32a __attribute__((may_alias));

#define NITER 8  // iters per wave; 512-thread block => 8 waves * 16 pts * 8 = 1024 pts/block

__device__ inline unsigned short f2b(float f) {  // f32 -> bf16 RNE (prep only)
    unsigned int x;
    __builtin_memcpy(&x, &f, 4);
    unsigned int r = (x + 0x7FFFu + ((x >> 16) & 1u)) >> 16;
    return (unsigned short)r;
}
__device__ inline unsigned int cvt_pk_bf16(float lo, float hi) {
    unsigned int r;
    asm("v_cvt_pk_bf16_f32 %0, %1, %2" : "=v"(r) : "v"(lo), "v"(hi));
    return r;
}
__device__ inline float vexp2(float x) { float r; asm("v_exp_f32 %0, %1" : "=v"(r) : "v"(x)); return r; }
__device__ inline float vlog2(float x) { float r; asm("v_log_f32 %0, %1" : "=v"(r) : "v"(x)); return r; }
__device__ inline float vrcp(float x)  { float r; asm("v_rcp_f32 %0, %1" : "=v"(r) : "v"(x)); return r; }
// softplus(x) = ln2 * log2(1 + 2^(x*log2e)) — 5 inst, 2 transcendental, f32-safe for |x|<80
__device__ inline float softplus_f(float x) {
    return 0.69314718f * vlog2(1.f + vexp2(1.44269504f * x));
}
__device__ inline float sigmoid_f(float x) {
    return vrcp(1.f + vexp2(-1.44269504f * x));
}
__device__ inline bf16x8 as_bf16x8(u32x4 v) { return __builtin_bit_cast(bf16x8, v); }

// ws layout: [0..287] f32 biases | byte 1152: ushort frag-major weights 36*64*8
// bias map: [0]ob0 [64]ob1 [128]ob2 [144]rb1 [208]rb2(pad->16) [224]rgb_b0'(folded latent)
// frag bases: occ0:0(Nt4,Kt1) occ1:4(4,2) occ2:12(1,2) rgb0:14(4,3) rgb1:26(4,2) rgb2:34(1,2)
// frag: lane l holds W[k=kt*32+(l>>4)*8+j][n=nt*16+(l&15)]
// rgb0 x-row map: k<32 emb, 32..58 dir(rows 32..58), 59..63 zero,
//                 64..95 feat tile: k-local kl=1..15 -> W row 58+kl, kl=0 & kl>=16 -> ZERO
//                 (feat k-index == raw occ2 output index; out0=occ-preact nulled by zero row)

__global__ __launch_bounds__(256) void prep_weights(
    const float* __restrict__ oW0, const float* __restrict__ ob0,
    const float* __restrict__ oW1, const float* __restrict__ ob1,
    const float* __restrict__ oW2, const float* __restrict__ ob2,
    const float* __restrict__ rW0, const float* __restrict__ rb0,
    const float* __restrict__ rW1, const float* __restrict__ rb1,
    const float* __restrict__ rW2, const float* __restrict__ rb2,
    const float* __restrict__ rlat, const int* __restrict__ lidx,
    float* __restrict__ wsf, ushort* __restrict__ wsw)
{
    const int bid = blockIdx.x, tid = threadIdx.x;
    __shared__ float red[256];

    if (bid == 0) {  // plain biases
        for (int i = tid; i < 224; i += 256) {
            float v;
            if (i < 64)       v = ob0[i];
            else if (i < 128) v = ob1[i - 64];
            else if (i < 144) v = ob2[i - 128];
            else if (i < 208) v = rb1[i - 144];
            else              v = (i - 208 < 3) ? rb2[i - 208] : 0.f;
            wsf[i] = v;
        }
    }
    if (bid == 7) {  // parallel latent fold: rgb_b0' = rgb_b0 + latent @ rgb_W0[74:202]
        const int outn = tid & 63, sl = tid >> 6;  // 4 slices x 32 k
        const float* lat = rlat + (size_t)lidx[0] * 128;
        float p = 0.f;
        for (int k = sl * 32; k < sl * 32 + 32; k++)
            p = fmaf(lat[k], rW0[(74 + k) * 64 + outn], p);
        red[tid] = p;
        __syncthreads();
        if (tid < 64)
            wsf[224 + tid] = rb0[tid] + red[tid] + red[64 + tid] + red[128 + tid] + red[192 + tid];
    }
    // fragment-major weight table: 2304 frag-lanes split across 8 blocks
    for (int t = tid; t < 288; t += 256) {
        const int s = bid * 288 + t;
        const int frag = s >> 6, lane = s & 63;
        const int qq = lane >> 4, cc = lane & 15;
        const float* W;
        int ldn = 64, nt = 0, kt = 0;
        bool isr0 = false, isr2 = false;
        if (frag < 4)       { W = oW0; nt = frag; kt = 0; }
        else if (frag < 12) { W = oW1; int f = frag - 4;  nt = f >> 1; kt = f & 1; }
        else if (frag < 14) { W = oW2; ldn = 16; nt = 0; kt = frag - 12; }
        else if (frag < 26) { W = rW0; int f = frag - 14; nt = f / 3; kt = f - nt * 3; isr0 = true; }
        else if (frag < 34) { W = rW1; int f = frag - 26; nt = f >> 1; kt = f & 1; }
        else                { W = rW2; ldn = 3; nt = 0; kt = frag - 34; isr2 = true; }
        const int nn = nt * 16 + cc;
        __align__(16) ushort vals[8];
#pragma unroll
        for (int j = 0; j < 8; j++) {
            int k = kt * 32 + qq * 8 + j;
            float v = 0.f;
            if (isr0) {
                int ks = -1;
                if (k < 59) ks = k;                            // emb + dir rows
                else if (k >= 65 && k < 80) ks = k - 65 + 59;  // feat kl=1..15 -> rows 59..73
                if (ks >= 0) v = W[ks * 64 + nn];
            } else if (isr2) {
                if (nn < 3) v = W[k * 3 + nn];
            } else {
                v = W[k * ldn + nn];
            }
            vals[j] = f2b(v);
        }
        *(u32x4a*)&wsw[s * 8] = *(const u32x4a*)vals;
    }
}

// Transposed-compute kernel: D = W^T_tile · X^T_tile  (row=out, col=point).
// Lane (q=l>>4, c=l&15) holds outs nt*16+q*4+{0..3} of point c -> packed b64 writes.
// Biases live in LDS (s_b), NOT in 72 permanently-live VGPRs: at the
// __launch_bounds__(512,4) 128-VGPR cap, the bias cache starved the
// scheduler's ds_read lookahead. Opaque-pointer asm per iteration defeats
// LICM so invariant LDS loads re-issue (cheap) instead of hoisting into
// long-lived registers (spill/serialize).
__global__ __launch_bounds__(512, 4) void net_mfma(
    const float* __restrict__ emb, const float* __restrict__ dir,
    const float* __restrict__ wsf, const ushort* __restrict__ wsw,
    float* __restrict__ out, int n)
{
    __shared__ __align__(16) ushort s_w[36 * 64 * 8];    // 36,864 B
    __shared__ __align__(16) ushort s_h[8][16 * 72];     // 18,432 B  activations, ld=72
    __shared__ __align__(16) float s_b[288];             //  1,152 B  biases (f32)

    const int tid = threadIdx.x;
    for (int i = tid; i < 36 * 64; i += 512)
        *(u32x4a*)&s_w[i * 8] = *(const u32x4a*)(wsw + i * 8);
    for (int i = tid; i < 288; i += 512) s_b[i] = wsf[i];
    __syncthreads();

    const int wave = tid >> 6, lane = tid & 63, q = lane >> 4, c = lane & 15;
    ushort* hw = s_h[wave];
    // zero own activation slice once (garbage LDS could be NaN-patterned bf16)
    for (int i = lane; i < 576; i += 64) ((u32a*)hw)[i] = 0u;

    const int q4 = q * 4;
    const long dlim = (long)n * 27;

    for (int it = 0; it < NITER; ++it) {
        const ushort* sw = s_w;       // opaque per-iter bases: block LICM of the
        const float*  sb = s_b;       // 36 weight-frag + 18 bias LDS loads
        asm volatile("" : "+v"(sw), "+v"(sb));

        const long p0 = (long)blockIdx.x * 1024 + it * 128 + wave * 16;  // +c = point

        // ---- input B-fragments straight from global ----
        bf16x8 x_emb, x_dir;
        {
            const float* ep = emb + (p0 + c) * 32 + q * 8;
            f32x4 e0 = *(const f32x4a*)ep;
            f32x4 e1 = *(const f32x4a*)(ep + 4);
            u32x4 pk = {cvt_pk_bf16(e0[0], e0[1]), cvt_pk_bf16(e0[2], e0[3]),
                        cvt_pk_bf16(e1[0], e1[1]), cvt_pk_bf16(e1[2], e1[3])};
            x_emb = as_bf16x8(pk);
        }
        {
            const long ib = (p0 + c) * 27 + q * 8;
            f32x4 d0, d1;
            if (ib + 8 <= dlim) {          // all but one wave in the grid
                d0 = *(const f32x4a*)(dir + ib);
                d1 = *(const f32x4a*)(dir + ib + 4);
            } else {                       // final point, q=3: guard OOB
#pragma unroll
                for (int j = 0; j < 4; j++) d0[j] = (ib + j < dlim) ? dir[ib + j] : 0.f;
#pragma unroll
                for (int j = 0; j < 4; j++) d1[j] = (ib + 4 + j < dlim) ? dir[ib + 4 + j] : 0.f;
            }
            // k-local >= 27 lanes carry garbage; rgb0 dir weight rows 27..31 are zero
            u32x4 pk = {cvt_pk_bf16(d0[0], d0[1]), cvt_pk_bf16(d0[2], d0[3]),
                        cvt_pk_bf16(d1[0], d1[1]), cvt_pk_bf16(d1[2], d1[3])};
            x_dir = as_bf16x8(pk);
        }

        // ---- occ layer 0: K=32 (emb), out 64 ----
#pragma unroll
        for (int nt = 0; nt < 4; ++nt) {
            f32x4 acc = *(const f32x4a*)&sb[0 + nt * 16 + q4];
            acc = __builtin_amdgcn_mfma_f32_16x16x32_bf16(
                as_bf16x8(*(const u32x4a*)&sw[((0 + nt) * 64 + lane) * 8]), x_emb, acc, 0, 0, 0);
            u32x2 pk = {cvt_pk_bf16(softplus_f(acc[0]), softplus_f(acc[1])),
                        cvt_pk_bf16(softplus_f(acc[2]), softplus_f(acc[3]))};
            *(u32x2a*)&hw[c * 72 + nt * 16 + q4] = pk;
        }
        // ---- occ layer 1: K=64, out 64 ----
        {
            bf16x8 h0 = as_bf16x8(*(const u32x4a*)&hw[c * 72 + 0 + q * 8]);
            bf16x8 h1 = as_bf16x8(*(const u32x4a*)&hw[c * 72 + 32 + q * 8]);
#pragma unroll
            for (int nt = 0; nt < 4; ++nt) {
                f32x4 acc = *(const f32x4a*)&sb[64 + nt * 16 + q4];
                acc = __builtin_amdgcn_mfma_f32_16x16x32_bf16(
                    as_bf16x8(*(const u32x4a*)&sw[((4 + nt * 2 + 0) * 64 + lane) * 8]), h0, acc, 0, 0, 0);
                acc = __builtin_amdgcn_mfma_f32_16x16x32_bf16(
                    as_bf16x8(*(const u32x4a*)&sw[((4 + nt * 2 + 1) * 64 + lane) * 8]), h1, acc, 0, 0, 0);
                u32x2 pk = {cvt_pk_bf16(softplus_f(acc[0]), softplus_f(acc[1])),
                            cvt_pk_bf16(softplus_f(acc[2]), softplus_f(acc[3]))};
                *(u32x2a*)&hw[c * 72 + nt * 16 + q4] = pk;
            }
        }
        // ---- occ layer 2: K=64, out 16 (raw outs -> feat region k=0..15; occ = sigmoid(out0)) ----
        float occv;
        {
            bf16x8 h0 = as_bf16x8(*(const u32x4a*)&hw[c * 72 + 0 + q * 8]);
            bf16x8 h1 = as_bf16x8(*(const u32x4a*)&hw[c * 72 + 32 + q * 8]);
            f32x4 acc = *(const f32x4a*)&sb[128 + q4];
            acc = __builtin_amdgcn_mfma_f32_16x16x32_bf16(
                as_bf16x8(*(const u32x4a*)&sw[(12 * 64 + lane) * 8]), h0, acc, 0, 0, 0);
            acc = __builtin_amdgcn_mfma_f32_16x16x32_bf16(
                as_bf16x8(*(const u32x4a*)&sw[(13 * 64 + lane) * 8]), h1, acc, 0, 0, 0);
            occv = sigmoid_f(acc[0]);  // 1-exp(-softplus(h)) == sigmoid(h); valid on q==0
            u32x2 pk = {cvt_pk_bf16(acc[0], acc[1]), cvt_pk_bf16(acc[2], acc[3])};
            *(u32x2a*)&hw[c * 72 + q4] = pk;  // raw outs 0..15 (out0 nulled by zero weight row)
        }
        // ---- rgb layer 0: K=96 (emb|dir|feat), out 64, bias = folded rgb_b0' ----
        {
            // q>=2 reads stale h (k-local 16..31): finite garbage x zero weight rows
            bf16x8 x_feat = as_bf16x8(*(const u32x4a*)&hw[c * 72 + q * 8]);
#pragma unroll
            for (int nt = 0; nt < 4; ++nt) {
                f32x4 acc = *(const f32x4a*)&sb[224 + nt * 16 + q4];
                acc = __builtin_amdgcn_mfma_f32_16x16x32_bf16(
                    as_bf16x8(*(const u32x4a*)&sw[((14 + nt * 3 + 0) * 64 + lane) * 8]), x_emb, acc, 0, 0, 0);
                acc = __builtin_amdgcn_mfma_f32_16x16x32_bf16(
                    as_bf16x8(*(const u32x4a*)&sw[((14 + nt * 3 + 1) * 64 + lane) * 8]), x_dir, acc, 0, 0, 0);
                acc = __builtin_amdgcn_mfma_f32_16x16x32_bf16(
                    as_bf16x8(*(const u32x4a*)&sw[((14 + nt * 3 + 2) * 64 + lane) * 8]), x_feat, acc, 0, 0, 0);
                u32x2 pk = {cvt_pk_bf16(softplus_f(acc[0]), softplus_f(acc[1])),
                            cvt_pk_bf16(softplus_f(acc[2]), softplus_f(acc[3]))};
                *(u32x2a*)&hw[c * 72 + nt * 16 + q4] = pk;
            }
        }
        // ---- rgb layer 1: K=64, out 64 ----
        {
            bf16x8 h0 = as_bf16x8(*(const u32x4a*)&hw[c * 72 + 0 + q * 8]);
            bf16x8 h1 = as_bf16x8(*(const u32x4a*)&hw[c * 72 + 32 + q * 8]);
#pragma unroll
            for (int nt = 0; nt < 4; ++nt) {
                f32x4 acc = *(const f32x4a*)&sb[144 + nt * 16 + q4];
                acc = __builtin_amdgcn_mfma_f32_16x16x32_bf16(
                    as_bf16x8(*(const u32x4a*)&sw[((26 + nt * 2 + 0) * 64 + lane) * 8]), h0, acc, 0, 0, 0);
                acc = __builtin_amdgcn_mfma_f32_16x16x32_bf16(
                    as_bf16x8(*(const u32x4a*)&sw[((26 + nt * 2 + 1) * 64 + lane) * 8]), h1, acc, 0, 0, 0);
                u32x2 pk = {cvt_pk_bf16(softplus_f(acc[0]), softplus_f(acc[1])),
                            cvt_pk_bf16(softplus_f(acc[2]), softplus_f(acc[3]))};
                *(u32x2a*)&hw[c * 72 + nt * 16 + q4] = pk;
            }
        }
        // ---- rgb layer 2: K=64, outs 0..2 (sigmoid) + epilogue ----
        {
            bf16x8 h0 = as_bf16x8(*(const u32x4a*)&hw[c * 72 + 0 + q * 8]);
            bf16x8 h1 = as_bf16x8(*(const u32x4a*)&hw[c * 72 + 32 + q * 8]);
            f32x4 acc = *(const f32x4a*)&sb[208 + q4];
            acc = __builtin_amdgcn_mfma_f32_16x16x32_bf16(
                as_bf16x8(*(const u32x4a*)&sw[(34 * 64 + lane) * 8]), h0, acc, 0, 0, 0);
            acc = __builtin_amdgcn_mfma_f32_16x16x32_bf16(
                as_bf16x8(*(const u32x4a*)&sw[(35 * 64 + lane) * 8]), h1, acc, 0, 0, 0);
            if (q == 0) {  // lane c holds all channels of point p0+c
                f32x4 o;
                o[0] = sigmoid_f(acc[0]);
                o[1] = sigmoid_f(acc[1]);
                o[2] = sigmoid_f(acc[2]);
                o[3] = occv;
                *(f32x4a*)&out[(p0 + c) * 4] = o;
                out[(long)4 * n + p0 + c] = occv;
            }
        }
    }
}

extern "C" void kernel_launch(void* const* d_in, const int* in_sizes, int n_in,
                              void* d_out, int out_size, void* d_ws, size_t ws_size,
                              hipStream_t stream) {
    const int n = in_sizes[0] / 32;  // N = 524288
    float*  wsf = (float*)d_ws;
    ushort* wsw = (ushort*)((char*)d_ws + 1152);
    prep_weights<<<8, 256, 0, stream>>>(
        (const float*)d_in[2], (const float*)d_in[3],
        (const float*)d_in[4], (const float*)d_in[5],
        (const float*)d_in[6], (const float*)d_in[7],
        (const float*)d_in[8], (const float*)d_in[9],
        (const float*)d_in[10], (const float*)d_in[11],
        (const float*)d_in[12], (const float*)d_in[13],
        (const float*)d_in[14], (const int*)d_in[15],
        wsf, wsw);
    net_mfma<<<n / 1024, 512, 0, stream>>>(
        (const float*)d_in[0], (const float*)d_in[1],
        wsf, wsw, (float*)d_out, n);
}

// Round 3
// 234.403 us; speedup vs baseline: 1.0059x; 1.0059x over previous
//
#include <hip/hip_runtime.h>

typedef __bf16 bf16x8 __attribute__((ext_vector_type(8)));
typedef float f32x4 __attribute__((ext_vector_type(4)));
typedef unsigned int u32x4 __attribute__((ext_vector_type(4)));
typedef unsigned int u32x2 __attribute__((ext_vector_type(2)));
typedef u32x4 u32x4a __attribute__((may_alias));
typedef u32x2 u32x2a __attribute__((may_alias));
typedef f32x4 f32x4a __attribute__((may_alias));
typedef unsigned int u32a __attribute__((may_alias));

#define NITER 4  // iters per wave; 1024-thread block => 16 waves * 16 pts * 4 = 1024 pts/block

__device__ inline unsigned short f2b(float f) {  // f32 -> bf16 RNE (prep only)
    unsigned int x;
    __builtin_memcpy(&x, &f, 4);
    unsigned int r = (x + 0x7FFFu + ((x >> 16) & 1u)) >> 16;
    return (unsigned short)r;
}
__device__ inline unsigned int cvt_pk_bf16(float lo, float hi) {
    unsigned int r;
    asm("v_cvt_pk_bf16_f32 %0, %1, %2" : "=v"(r) : "v"(lo), "v"(hi));
    return r;
}
__device__ inline float vexp2(float x) { float r; asm("v_exp_f32 %0, %1" : "=v"(r) : "v"(x)); return r; }
__device__ inline float vlog2(float x) { float r; asm("v_log_f32 %0, %1" : "=v"(r) : "v"(x)); return r; }
__device__ inline float vrcp(float x)  { float r; asm("v_rcp_f32 %0, %1" : "=v"(r) : "v"(x)); return r; }
// softplus(x) = ln2 * log2(1 + 2^(x*log2e)) — 5 inst, 2 transcendental, f32-safe for |x|<80
__device__ inline float softplus_f(float x) {
    return 0.69314718f * vlog2(1.f + vexp2(1.44269504f * x));
}
__device__ inline float sigmoid_f(float x) {
    return vrcp(1.f + vexp2(-1.44269504f * x));
}
__device__ inline bf16x8 as_bf16x8(u32x4 v) { return __builtin_bit_cast(bf16x8, v); }

// ws layout: [0..287] f32 biases | byte 1152: ushort frag-major weights 36*64*8
// bias map: [0]ob0 [64]ob1 [128]ob2 [144]rb1 [208]rb2(pad->16) [224]rgb_b0'(folded latent)
// frag bases: occ0:0(Nt4,Kt1) occ1:4(4,2) occ2:12(1,2) rgb0:14(4,3) rgb1:26(4,2) rgb2:34(1,2)
// frag: lane l holds W[k=kt*32+(l>>4)*8+j][n=nt*16+(l&15)]
// rgb0 x-row map: k<32 emb, 32..58 dir(rows 32..58), 59..63 zero,
//                 64..95 feat tile: k-local kl=1..15 -> W row 58+kl, kl=0 & kl>=16 -> ZERO
//                 (feat k-index == raw occ2 output index; out0=occ-preact nulled by zero row)

__global__ __launch_bounds__(256) void prep_weights(
    const float* __restrict__ oW0, const float* __restrict__ ob0,
    const float* __restrict__ oW1, const float* __restrict__ ob1,
    const float* __restrict__ oW2, const float* __restrict__ ob2,
    const float* __restrict__ rW0, const float* __restrict__ rb0,
    const float* __restrict__ rW1, const float* __restrict__ rb1,
    const float* __restrict__ rW2, const float* __restrict__ rb2,
    const float* __restrict__ rlat, const int* __restrict__ lidx,
    float* __restrict__ wsf, ushort* __restrict__ wsw)
{
    const int bid = blockIdx.x, tid = threadIdx.x;
    __shared__ float red[256];

    if (bid == 0) {  // plain biases
        for (int i = tid; i < 224; i += 256) {
            float v;
            if (i < 64)       v = ob0[i];
            else if (i < 128) v = ob1[i - 64];
            else if (i < 144) v = ob2[i - 128];
            else if (i < 208) v = rb1[i - 144];
            else              v = (i - 208 < 3) ? rb2[i - 208] : 0.f;
            wsf[i] = v;
        }
    }
    if (bid == 7) {  // parallel latent fold: rgb_b0' = rgb_b0 + latent @ rgb_W0[74:202]
        const int outn = tid & 63, sl = tid >> 6;  // 4 slices x 32 k
        const float* lat = rlat + (size_t)lidx[0] * 128;
        float p = 0.f;
        for (int k = sl * 32; k < sl * 32 + 32; k++)
            p = fmaf(lat[k], rW0[(74 + k) * 64 + outn], p);
        red[tid] = p;
        __syncthreads();
        if (tid < 64)
            wsf[224 + tid] = rb0[tid] + red[tid] + red[64 + tid] + red[128 + tid] + red[192 + tid];
    }
    // fragment-major weight table: 2304 frag-lanes split across 8 blocks
    for (int t = tid; t < 288; t += 256) {
        const int s = bid * 288 + t;
        const int frag = s >> 6, lane = s & 63;
        const int qq = lane >> 4, cc = lane & 15;
        const float* W;
        int ldn = 64, nt = 0, kt = 0;
        bool isr0 = false, isr2 = false;
        if (frag < 4)       { W = oW0; nt = frag; kt = 0; }
        else if (frag < 12) { W = oW1; int f = frag - 4;  nt = f >> 1; kt = f & 1; }
        else if (frag < 14) { W = oW2; ldn = 16; nt = 0; kt = frag - 12; }
        else if (frag < 26) { W = rW0; int f = frag - 14; nt = f / 3; kt = f - nt * 3; isr0 = true; }
        else if (frag < 34) { W = rW1; int f = frag - 26; nt = f >> 1; kt = f & 1; }
        else                { W = rW2; ldn = 3; nt = 0; kt = frag - 34; isr2 = true; }
        const int nn = nt * 16 + cc;
        __align__(16) ushort vals[8];
#pragma unroll
        for (int j = 0; j < 8; j++) {
            int k = kt * 32 + qq * 8 + j;
            float v = 0.f;
            if (isr0) {
                int ks = -1;
                if (k < 59) ks = k;                            // emb + dir rows
                else if (k >= 65 && k < 80) ks = k - 65 + 59;  // feat kl=1..15 -> rows 59..73
                if (ks >= 0) v = W[ks * 64 + nn];
            } else if (isr2) {
                if (nn < 3) v = W[k * 3 + nn];
            } else {
                v = W[k * ldn + nn];
            }
            vals[j] = f2b(v);
        }
        *(u32x4a*)&wsw[s * 8] = *(const u32x4a*)vals;
    }
}

// Transposed-compute kernel: D = W^T_tile · X^T_tile  (row=out, col=point).
// Lane (q=l>>4, c=l&15) holds outs nt*16+q*4+{0..3} of point c -> packed b64 writes.
// 1024-thread block (16 waves): LDS = 36864(s_w) + 36864(s_h) + 1152(s_b) = 74,880 B
// -> 2 blocks/CU x 16 waves = 32 waves/CU (100% occupancy). VGPR=52 fits the
// 8-waves/SIMD <=64-VGPR requirement pinned by __launch_bounds__(1024,8).
// Biases in LDS (not 72 live VGPRs); opaque per-iter bases defeat LICM so
// invariant LDS loads re-issue cheaply instead of pinning registers.
__global__ __launch_bounds__(1024, 8) void net_mfma(
    const float* __restrict__ emb, const float* __restrict__ dir,
    const float* __restrict__ wsf, const ushort* __restrict__ wsw,
    float* __restrict__ out, int n)
{
    __shared__ __align__(16) ushort s_w[36 * 64 * 8];    // 36,864 B
    __shared__ __align__(16) ushort s_h[16][16 * 72];    // 36,864 B  activations, ld=72
    __shared__ __align__(16) float s_b[288];             //  1,152 B  biases (f32)

    const int tid = threadIdx.x;
    for (int i = tid; i < 36 * 64; i += 1024)
        *(u32x4a*)&s_w[i * 8] = *(const u32x4a*)(wsw + i * 8);
    for (int i = tid; i < 288; i += 1024) s_b[i] = wsf[i];
    __syncthreads();

    const int wave = tid >> 6, lane = tid & 63, q = lane >> 4, c = lane & 15;
    ushort* hw = s_h[wave];
    // zero own activation slice once (garbage LDS could be NaN-patterned bf16)
    for (int i = lane; i < 576; i += 64) ((u32a*)hw)[i] = 0u;

    const int q4 = q * 4;
    const long dlim = (long)n * 27;

    for (int it = 0; it < NITER; ++it) {
        const ushort* sw = s_w;       // opaque per-iter bases: block LICM of the
        const float*  sb = s_b;       // 36 weight-frag + 18 bias LDS loads
        asm volatile("" : "+v"(sw), "+v"(sb));

        const long p0 = (long)blockIdx.x * 1024 + it * 256 + wave * 16;  // +c = point

        // ---- input B-fragments straight from global ----
        bf16x8 x_emb, x_dir;
        {
            const float* ep = emb + (p0 + c) * 32 + q * 8;
            f32x4 e0 = *(const f32x4a*)ep;
            f32x4 e1 = *(const f32x4a*)(ep + 4);
            u32x4 pk = {cvt_pk_bf16(e0[0], e0[1]), cvt_pk_bf16(e0[2], e0[3]),
                        cvt_pk_bf16(e1[0], e1[1]), cvt_pk_bf16(e1[2], e1[3])};
            x_emb = as_bf16x8(pk);
        }
        {
            const long ib = (p0 + c) * 27 + q * 8;
            f32x4 d0, d1;
            if (ib + 8 <= dlim) {          // all but one wave in the grid
                d0 = *(const f32x4a*)(dir + ib);
                d1 = *(const f32x4a*)(dir + ib + 4);
            } else {                       // final point, q=3: guard OOB
#pragma unroll
                for (int j = 0; j < 4; j++) d0[j] = (ib + j < dlim) ? dir[ib + j] : 0.f;
#pragma unroll
                for (int j = 0; j < 4; j++) d1[j] = (ib + 4 + j < dlim) ? dir[ib + 4 + j] : 0.f;
            }
            // k-local >= 27 lanes carry garbage; rgb0 dir weight rows 27..31 are zero
            u32x4 pk = {cvt_pk_bf16(d0[0], d0[1]), cvt_pk_bf16(d0[2], d0[3]),
                        cvt_pk_bf16(d1[0], d1[1]), cvt_pk_bf16(d1[2], d1[3])};
            x_dir = as_bf16x8(pk);
        }

        // ---- occ layer 0: K=32 (emb), out 64 ----
#pragma unroll
        for (int nt = 0; nt < 4; ++nt) {
            f32x4 acc = *(const f32x4a*)&sb[0 + nt * 16 + q4];
            acc = __builtin_amdgcn_mfma_f32_16x16x32_bf16(
                as_bf16x8(*(const u32x4a*)&sw[((0 + nt) * 64 + lane) * 8]), x_emb, acc, 0, 0, 0);
            u32x2 pk = {cvt_pk_bf16(softplus_f(acc[0]), softplus_f(acc[1])),
                        cvt_pk_bf16(softplus_f(acc[2]), softplus_f(acc[3]))};
            *(u32x2a*)&hw[c * 72 + nt * 16 + q4] = pk;
        }
        // ---- occ layer 1: K=64, out 64 ----
        {
            bf16x8 h0 = as_bf16x8(*(const u32x4a*)&hw[c * 72 + 0 + q * 8]);
            bf16x8 h1 = as_bf16x8(*(const u32x4a*)&hw[c * 72 + 32 + q * 8]);
#pragma unroll
            for (int nt = 0; nt < 4; ++nt) {
                f32x4 acc = *(const f32x4a*)&sb[64 + nt * 16 + q4];
                acc = __builtin_amdgcn_mfma_f32_16x16x32_bf16(
                    as_bf16x8(*(const u32x4a*)&sw[((4 + nt * 2 + 0) * 64 + lane) * 8]), h0, acc, 0, 0, 0);
                acc = __builtin_amdgcn_mfma_f32_16x16x32_bf16(
                    as_bf16x8(*(const u32x4a*)&sw[((4 + nt * 2 + 1) * 64 + lane) * 8]), h1, acc, 0, 0, 0);
                u32x2 pk = {cvt_pk_bf16(softplus_f(acc[0]), softplus_f(acc[1])),
                            cvt_pk_bf16(softplus_f(acc[2]), softplus_f(acc[3]))};
                *(u32x2a*)&hw[c * 72 + nt * 16 + q4] = pk;
            }
        }
        // ---- occ layer 2: K=64, out 16 (raw outs -> feat region k=0..15; occ = sigmoid(out0)) ----
        float occv;
        {
            bf16x8 h0 = as_bf16x8(*(const u32x4a*)&hw[c * 72 + 0 + q * 8]);
            bf16x8 h1 = as_bf16x8(*(const u32x4a*)&hw[c * 72 + 32 + q * 8]);
            f32x4 acc = *(const f32x4a*)&sb[128 + q4];
            acc = __builtin_amdgcn_mfma_f32_16x16x32_bf16(
                as_bf16x8(*(const u32x4a*)&sw[(12 * 64 + lane) * 8]), h0, acc, 0, 0, 0);
            acc = __builtin_amdgcn_mfma_f32_16x16x32_bf16(
                as_bf16x8(*(const u32x4a*)&sw[(13 * 64 + lane) * 8]), h1, acc, 0, 0, 0);
            occv = sigmoid_f(acc[0]);  // 1-exp(-softplus(h)) == sigmoid(h); valid on q==0
            u32x2 pk = {cvt_pk_bf16(acc[0], acc[1]), cvt_pk_bf16(acc[2], acc[3])};
            *(u32x2a*)&hw[c * 72 + q4] = pk;  // raw outs 0..15 (out0 nulled by zero weight row)
        }
        // ---- rgb layer 0: K=96 (emb|dir|feat), out 64, bias = folded rgb_b0' ----
        {
            // q>=2 reads stale h (k-local 16..31): finite garbage x zero weight rows
            bf16x8 x_feat = as_bf16x8(*(const u32x4a*)&hw[c * 72 + q * 8]);
#pragma unroll
            for (int nt = 0; nt < 4; ++nt) {
                f32x4 acc = *(const f32x4a*)&sb[224 + nt * 16 + q4];
                acc = __builtin_amdgcn_mfma_f32_16x16x32_bf16(
                    as_bf16x8(*(const u32x4a*)&sw[((14 + nt * 3 + 0) * 64 + lane) * 8]), x_emb, acc, 0, 0, 0);
                acc = __builtin_amdgcn_mfma_f32_16x16x32_bf16(
                    as_bf16x8(*(const u32x4a*)&sw[((14 + nt * 3 + 1) * 64 + lane) * 8]), x_dir, acc, 0, 0, 0);
                acc = __builtin_amdgcn_mfma_f32_16x16x32_bf16(
                    as_bf16x8(*(const u32x4a*)&sw[((14 + nt * 3 + 2) * 64 + lane) * 8]), x_feat, acc, 0, 0, 0);
                u32x2 pk = {cvt_pk_bf16(softplus_f(acc[0]), softplus_f(acc[1])),
                            cvt_pk_bf16(softplus_f(acc[2]), softplus_f(acc[3]))};
                *(u32x2a*)&hw[c * 72 + nt * 16 + q4] = pk;
            }
        }
        // ---- rgb layer 1: K=64, out 64 ----
        {
            bf16x8 h0 = as_bf16x8(*(const u32x4a*)&hw[c * 72 + 0 + q * 8]);
            bf16x8 h1 = as_bf16x8(*(const u32x4a*)&hw[c * 72 + 32 + q * 8]);
#pragma unroll
            for (int nt = 0; nt < 4; ++nt) {
                f32x4 acc = *(const f32x4a*)&sb[144 + nt * 16 + q4];
                acc = __builtin_amdgcn_mfma_f32_16x16x32_bf16(
                    as_bf16x8(*(const u32x4a*)&sw[((26 + nt * 2 + 0) * 64 + lane) * 8]), h0, acc, 0, 0, 0);
                acc = __builtin_amdgcn_mfma_f32_16x16x32_bf16(
                    as_bf16x8(*(const u32x4a*)&sw[((26 + nt * 2 + 1) * 64 + lane) * 8]), h1, acc, 0, 0, 0);
                u32x2 pk = {cvt_pk_bf16(softplus_f(acc[0]), softplus_f(acc[1])),
                            cvt_pk_bf16(softplus_f(acc[2]), softplus_f(acc[3]))};
                *(u32x2a*)&hw[c * 72 + nt * 16 + q4] = pk;
            }
        }
        // ---- rgb layer 2: K=64, outs 0..2 (sigmoid) + epilogue ----
        {
            bf16x8 h0 = as_bf16x8(*(const u32x4a*)&hw[c * 72 + 0 + q * 8]);
            bf16x8 h1 = as_bf16x8(*(const u32x4a*)&hw[c * 72 + 32 + q * 8]);
            f32x4 acc = *(const f32x4a*)&sb[208 + q4];
            acc = __builtin_amdgcn_mfma_f32_16x16x32_bf16(
                as_bf16x8(*(const u32x4a*)&sw[(34 * 64 + lane) * 8]), h0, acc, 0, 0, 0);
            acc = __builtin_amdgcn_mfma_f32_16x16x32_bf16(
                as_bf16x8(*(const u32x4a*)&sw[(35 * 64 + lane) * 8]), h1, acc, 0, 0, 0);
            if (q == 0) {  // lane c holds all channels of point p0+c
                f32x4 o;
                o[0] = sigmoid_f(acc[0]);
                o[1] = sigmoid_f(acc[1]);
                o[2] = sigmoid_f(acc[2]);
                o[3] = occv;
                *(f32x4a*)&out[(p0 + c) * 4] = o;
                out[(long)4 * n + p0 + c] = occv;
            }
        }
    }
}

extern "C" void kernel_launch(void* const* d_in, const int* in_sizes, int n_in,
                              void* d_out, int out_size, void* d_ws, size_t ws_size,
                              hipStream_t stream) {
    const int n = in_sizes[0] / 32;  // N = 524288
    float*  wsf = (float*)d_ws;
    ushort* wsw = (ushort*)((char*)d_ws + 1152);
    prep_weights<<<8, 256, 0, stream>>>(
        (const float*)d_in[2], (const float*)d_in[3],
        (const float*)d_in[4], (const float*)d_in[5],
        (const float*)d_in[6], (const float*)d_in[7],
        (const float*)d_in[8], (const float*)d_in[9],
        (const float*)d_in[10], (const float*)d_in[11],
        (const float*)d_in[12], (const float*)d_in[13],
        (const float*)d_in[14], (const int*)d_in[15],
        wsf, wsw);
    net_mfma<<<n / 1024, 1024, 0, stream>>>(
        (const float*)d_in[0], (const float*)d_in[1],
        wsf, wsw, (float*)d_out, n);
}

// Round 4
// 207.599 us; speedup vs baseline: 1.1357x; 1.1291x over previous
//
#include <hip/hip_runtime.h>

typedef __bf16 bf16x8 __attribute__((ext_vector_type(8)));
typedef float f32x4 __attribute__((ext_vector_type(4)));
typedef unsigned int u32x4 __attribute__((ext_vector_type(4)));
typedef unsigned int u32x2 __attribute__((ext_vector_type(2)));
typedef u32x4 u32x4a __attribute__((may_alias));
typedef u32x2 u32x2a __attribute__((may_alias));
typedef f32x4 f32x4a __attribute__((may_alias));
typedef unsigned int u32a __attribute__((may_alias));

#define NITER 4  // 512-thread block => 8 waves * 32 pts * 4 = 1024 pts/block

__device__ inline unsigned short f2b(float f) {  // f32 -> bf16 RNE (prep only)
    unsigned int x;
    __builtin_memcpy(&x, &f, 4);
    unsigned int r = (x + 0x7FFFu + ((x >> 16) & 1u)) >> 16;
    return (unsigned short)r;
}
__device__ inline unsigned int cvt_pk_bf16(float lo, float hi) {
    unsigned int r;
    asm("v_cvt_pk_bf16_f32 %0, %1, %2" : "=v"(r) : "v"(lo), "v"(hi));
    return r;
}
__device__ inline float vexp2(float x) { float r; asm("v_exp_f32 %0, %1" : "=v"(r) : "v"(x)); return r; }
__device__ inline float vlog2(float x) { float r; asm("v_log_f32 %0, %1" : "=v"(r) : "v"(x)); return r; }
__device__ inline float vrcp(float x)  { float r; asm("v_rcp_f32 %0, %1" : "=v"(r) : "v"(x)); return r; }
// softplus(x) = ln2 * log2(1 + 2^(x*log2e)) — f32-safe for |x|<80
__device__ inline float softplus_f(float x) {
    return 0.69314718f * vlog2(1.f + vexp2(1.44269504f * x));
}
__device__ inline float sigmoid_f(float x) {
    return vrcp(1.f + vexp2(-1.44269504f * x));
}
__device__ inline bf16x8 as_bf16x8(u32x4 v) { return __builtin_bit_cast(bf16x8, v); }

// softplus + pack to bf16x4 + b64 store
#define SPST(dstp, acc) { \
    u32x2 pk_ = {cvt_pk_bf16(softplus_f((acc)[0]), softplus_f((acc)[1])), \
                 cvt_pk_bf16(softplus_f((acc)[2]), softplus_f((acc)[3]))}; \
    *(u32x2a*)(dstp) = pk_; }

// ws layout: [0..287] f32 biases | byte 1152: ushort frag-major weights 36*64*8
// bias map: [0]ob0 [64]ob1 [128]ob2 [144]rb1 [208]rb2(pad->16) [224]rgb_b0'(folded latent)
// frag bases: occ0:0(Nt4,Kt1) occ1:4(4,2) occ2:12(1,2) rgb0:14(4,3) rgb1:26(4,2) rgb2:34(1,2)
// frag: lane l holds W[k=kt*32+(l>>4)*8+j][n=nt*16+(l&15)]
// rgb0 x-row map: k<32 emb, 32..58 dir(rows 32..58), 59..63 zero,
//                 64..95 feat tile: k-local kl=1..15 -> W row 58+kl, kl=0 & kl>=16 -> ZERO

__global__ __launch_bounds__(256) void prep_weights(
    const float* __restrict__ oW0, const float* __restrict__ ob0,
    const float* __restrict__ oW1, const float* __restrict__ ob1,
    const float* __restrict__ oW2, const float* __restrict__ ob2,
    const float* __restrict__ rW0, const float* __restrict__ rb0,
    const float* __restrict__ rW1, const float* __restrict__ rb1,
    const float* __restrict__ rW2, const float* __restrict__ rb2,
    const float* __restrict__ rlat, const int* __restrict__ lidx,
    float* __restrict__ wsf, ushort* __restrict__ wsw)
{
    const int bid = blockIdx.x, tid = threadIdx.x;
    __shared__ float red[256];

    if (bid == 0) {  // plain biases
        for (int i = tid; i < 224; i += 256) {
            float v;
            if (i < 64)       v = ob0[i];
            else if (i < 128) v = ob1[i - 64];
            else if (i < 144) v = ob2[i - 128];
            else if (i < 208) v = rb1[i - 144];
            else              v = (i - 208 < 3) ? rb2[i - 208] : 0.f;
            wsf[i] = v;
        }
    }
    if (bid == 7) {  // parallel latent fold: rgb_b0' = rgb_b0 + latent @ rgb_W0[74:202]
        const int outn = tid & 63, sl = tid >> 6;  // 4 slices x 32 k
        const float* lat = rlat + (size_t)lidx[0] * 128;
        float p = 0.f;
        for (int k = sl * 32; k < sl * 32 + 32; k++)
            p = fmaf(lat[k], rW0[(74 + k) * 64 + outn], p);
        red[tid] = p;
        __syncthreads();
        if (tid < 64)
            wsf[224 + tid] = rb0[tid] + red[tid] + red[64 + tid] + red[128 + tid] + red[192 + tid];
    }
    // fragment-major weight table: 2304 frag-lanes split across 8 blocks
    for (int t = tid; t < 288; t += 256) {
        const int s = bid * 288 + t;
        const int frag = s >> 6, lane = s & 63;
        const int qq = lane >> 4, cc = lane & 15;
        const float* W;
        int ldn = 64, nt = 0, kt = 0;
        bool isr0 = false, isr2 = false;
        if (frag < 4)       { W = oW0; nt = frag; kt = 0; }
        else if (frag < 12) { W = oW1; int f = frag - 4;  nt = f >> 1; kt = f & 1; }
        else if (frag < 14) { W = oW2; ldn = 16; nt = 0; kt = frag - 12; }
        else if (frag < 26) { W = rW0; int f = frag - 14; nt = f / 3; kt = f - nt * 3; isr0 = true; }
        else if (frag < 34) { W = rW1; int f = frag - 26; nt = f >> 1; kt = f & 1; }
        else                { W = rW2; ldn = 3; nt = 0; kt = frag - 34; isr2 = true; }
        const int nn = nt * 16 + cc;
        __align__(16) ushort vals[8];
#pragma unroll
        for (int j = 0; j < 8; j++) {
            int k = kt * 32 + qq * 8 + j;
            float v = 0.f;
            if (isr0) {
                int ks = -1;
                if (k < 59) ks = k;                            // emb + dir rows
                else if (k >= 65 && k < 80) ks = k - 65 + 59;  // feat kl=1..15 -> rows 59..73
                if (ks >= 0) v = W[ks * 64 + nn];
            } else if (isr2) {
                if (nn < 3) v = W[k * 3 + nn];
            } else {
                v = W[k * ldn + nn];
            }
            vals[j] = f2b(v);
        }
        *(u32x4a*)&wsw[s * 8] = *(const u32x4a*)vals;
    }
}

// Transposed-compute kernel: D = W^T_tile · X^T_tile (row=out, col=point).
// R4: 32 points/wave (two groups A: c, B: c+16). One weight-frag ds_read_b128
// feeds TWO MFMAs; one bias read feeds two accs -> LDS cycles/pt nearly halved
// (R3 showed LDS = top pipe at ~54%, occupancy changes neutral). 512-thr block,
// LDS = 36864(s_w)+36864(s_h 8x32x72)+1152(s_b) = 74,880 B -> 2 blocks/CU.
__global__ __launch_bounds__(512, 4) void net_mfma(
    const float* __restrict__ emb, const float* __restrict__ dir,
    const float* __restrict__ wsf, const ushort* __restrict__ wsw,
    float* __restrict__ out, int n)
{
    __shared__ __align__(16) ushort s_w[36 * 64 * 8];    // 36,864 B
    __shared__ __align__(16) ushort s_h[8][32 * 72];     // 36,864 B  activations, ld=72
    __shared__ __align__(16) float s_b[288];             //  1,152 B  biases (f32)

    const int tid = threadIdx.x;
    for (int i = tid; i < 36 * 64; i += 512)
        *(u32x4a*)&s_w[i * 8] = *(const u32x4a*)(wsw + i * 8);
    for (int i = tid; i < 288; i += 512) s_b[i] = wsf[i];
    __syncthreads();

    const int wave = tid >> 6, lane = tid & 63, q = lane >> 4, c = lane & 15;
    ushort* hw = s_h[wave];
    ushort* hA = hw + c * 72;          // group A point-row
    ushort* hB = hw + (c + 16) * 72;   // group B point-row
    // zero own activation slice once (garbage LDS could be NaN-patterned bf16)
    for (int i = lane; i < 1152; i += 64) ((u32a*)hw)[i] = 0u;

    const int q4 = q * 4, q8 = q * 8;
    const long dlim = (long)n * 27;

    for (int it = 0; it < NITER; ++it) {
        const ushort* sw = s_w;       // opaque per-iter bases: block LICM of the
        const float*  sb = s_b;       // weight-frag + bias LDS loads
        asm volatile("" : "+v"(sw), "+v"(sb));

        const long p0 = (long)blockIdx.x * 1024 + it * 256 + wave * 32;  // A: +c, B: +16+c

        // ---- input B-fragments straight from global (both groups) ----
        bf16x8 x_embA, x_embB, x_dirA, x_dirB;
        {
            const float* ep = emb + (p0 + c) * 32 + q8;
            f32x4 e0 = *(const f32x4a*)ep;
            f32x4 e1 = *(const f32x4a*)(ep + 4);
            u32x4 pk = {cvt_pk_bf16(e0[0], e0[1]), cvt_pk_bf16(e0[2], e0[3]),
                        cvt_pk_bf16(e1[0], e1[1]), cvt_pk_bf16(e1[2], e1[3])};
            x_embA = as_bf16x8(pk);
            const float* ep2 = emb + (p0 + 16 + c) * 32 + q8;
            f32x4 f0 = *(const f32x4a*)ep2;
            f32x4 f1 = *(const f32x4a*)(ep2 + 4);
            u32x4 pk2 = {cvt_pk_bf16(f0[0], f0[1]), cvt_pk_bf16(f0[2], f0[3]),
                         cvt_pk_bf16(f1[0], f1[1]), cvt_pk_bf16(f1[2], f1[3])};
            x_embB = as_bf16x8(pk2);
        }
        {
            // k-local >= 27 lanes carry garbage; rgb0 dir weight rows 27..31 are zero
            const long ibA = (p0 + c) * 27 + q8;
            f32x4 d0, d1;
            if (ibA + 8 <= dlim) {
                d0 = *(const f32x4a*)(dir + ibA);
                d1 = *(const f32x4a*)(dir + ibA + 4);
            } else {
#pragma unroll
                for (int j = 0; j < 4; j++) d0[j] = (ibA + j < dlim) ? dir[ibA + j] : 0.f;
#pragma unroll
                for (int j = 0; j < 4; j++) d1[j] = (ibA + 4 + j < dlim) ? dir[ibA + 4 + j] : 0.f;
            }
            u32x4 pk = {cvt_pk_bf16(d0[0], d0[1]), cvt_pk_bf16(d0[2], d0[3]),
                        cvt_pk_bf16(d1[0], d1[1]), cvt_pk_bf16(d1[2], d1[3])};
            x_dirA = as_bf16x8(pk);
            const long ibB = (p0 + 16 + c) * 27 + q8;
            f32x4 g0, g1;
            if (ibB + 8 <= dlim) {
                g0 = *(const f32x4a*)(dir + ibB);
                g1 = *(const f32x4a*)(dir + ibB + 4);
            } else {
#pragma unroll
                for (int j = 0; j < 4; j++) g0[j] = (ibB + j < dlim) ? dir[ibB + j] : 0.f;
#pragma unroll
                for (int j = 0; j < 4; j++) g1[j] = (ibB + 4 + j < dlim) ? dir[ibB + 4 + j] : 0.f;
            }
            u32x4 pk2 = {cvt_pk_bf16(g0[0], g0[1]), cvt_pk_bf16(g0[2], g0[3]),
                         cvt_pk_bf16(g1[0], g1[1]), cvt_pk_bf16(g1[2], g1[3])};
            x_dirB = as_bf16x8(pk2);
        }

        // ---- occ layer 0: K=32 (emb), out 64 ----
#pragma unroll
        for (int nt = 0; nt < 4; ++nt) {
            bf16x8 w = as_bf16x8(*(const u32x4a*)&sw[((0 + nt) * 64 + lane) * 8]);
            f32x4 b = *(const f32x4a*)&sb[0 + nt * 16 + q4];
            f32x4 aA = __builtin_amdgcn_mfma_f32_16x16x32_bf16(w, x_embA, b, 0, 0, 0);
            f32x4 aB = __builtin_amdgcn_mfma_f32_16x16x32_bf16(w, x_embB, b, 0, 0, 0);
            SPST(&hA[nt * 16 + q4], aA);
            SPST(&hB[nt * 16 + q4], aB);
        }
        // ---- occ layer 1: K=64, out 64 ----
        {
            bf16x8 hA0 = as_bf16x8(*(const u32x4a*)&hA[0 + q8]);
            bf16x8 hA1 = as_bf16x8(*(const u32x4a*)&hA[32 + q8]);
            bf16x8 hB0 = as_bf16x8(*(const u32x4a*)&hB[0 + q8]);
            bf16x8 hB1 = as_bf16x8(*(const u32x4a*)&hB[32 + q8]);
#pragma unroll
            for (int nt = 0; nt < 4; ++nt) {
                bf16x8 w0 = as_bf16x8(*(const u32x4a*)&sw[((4 + nt * 2 + 0) * 64 + lane) * 8]);
                bf16x8 w1 = as_bf16x8(*(const u32x4a*)&sw[((4 + nt * 2 + 1) * 64 + lane) * 8]);
                f32x4 b = *(const f32x4a*)&sb[64 + nt * 16 + q4];
                f32x4 aA = __builtin_amdgcn_mfma_f32_16x16x32_bf16(w0, hA0, b, 0, 0, 0);
                aA = __builtin_amdgcn_mfma_f32_16x16x32_bf16(w1, hA1, aA, 0, 0, 0);
                f32x4 aB = __builtin_amdgcn_mfma_f32_16x16x32_bf16(w0, hB0, b, 0, 0, 0);
                aB = __builtin_amdgcn_mfma_f32_16x16x32_bf16(w1, hB1, aB, 0, 0, 0);
                SPST(&hA[nt * 16 + q4], aA);
                SPST(&hB[nt * 16 + q4], aB);
            }
        }
        // ---- occ layer 2: K=64, out 16 (raw -> feat k=0..15; occ = sigmoid(out0)) ----
        float occA, occB;
        {
            bf16x8 hA0 = as_bf16x8(*(const u32x4a*)&hA[0 + q8]);
            bf16x8 hA1 = as_bf16x8(*(const u32x4a*)&hA[32 + q8]);
            bf16x8 hB0 = as_bf16x8(*(const u32x4a*)&hB[0 + q8]);
            bf16x8 hB1 = as_bf16x8(*(const u32x4a*)&hB[32 + q8]);
            bf16x8 w0 = as_bf16x8(*(const u32x4a*)&sw[(12 * 64 + lane) * 8]);
            bf16x8 w1 = as_bf16x8(*(const u32x4a*)&sw[(13 * 64 + lane) * 8]);
            f32x4 b = *(const f32x4a*)&sb[128 + q4];
            f32x4 aA = __builtin_amdgcn_mfma_f32_16x16x32_bf16(w0, hA0, b, 0, 0, 0);
            aA = __builtin_amdgcn_mfma_f32_16x16x32_bf16(w1, hA1, aA, 0, 0, 0);
            f32x4 aB = __builtin_amdgcn_mfma_f32_16x16x32_bf16(w0, hB0, b, 0, 0, 0);
            aB = __builtin_amdgcn_mfma_f32_16x16x32_bf16(w1, hB1, aB, 0, 0, 0);
            occA = sigmoid_f(aA[0]);  // 1-exp(-softplus(h)) == sigmoid(h); valid on q==0
            occB = sigmoid_f(aB[0]);
            u32x2 pkA = {cvt_pk_bf16(aA[0], aA[1]), cvt_pk_bf16(aA[2], aA[3])};
            *(u32x2a*)&hA[q4] = pkA;  // raw outs 0..15 (out0 nulled by zero weight row)
            u32x2 pkB = {cvt_pk_bf16(aB[0], aB[1]), cvt_pk_bf16(aB[2], aB[3])};
            *(u32x2a*)&hB[q4] = pkB;
        }
        // ---- rgb layer 0: K=96 (emb|dir|feat), out 64, bias = folded rgb_b0' ----
        {
            // q>=2 reads stale h (k-local 16..31): finite garbage x zero weight rows
            bf16x8 xfA = as_bf16x8(*(const u32x4a*)&hA[q8]);
            bf16x8 xfB = as_bf16x8(*(const u32x4a*)&hB[q8]);
#pragma unroll
            for (int nt = 0; nt < 4; ++nt) {
                bf16x8 w0 = as_bf16x8(*(const u32x4a*)&sw[((14 + nt * 3 + 0) * 64 + lane) * 8]);
                bf16x8 w1 = as_bf16x8(*(const u32x4a*)&sw[((14 + nt * 3 + 1) * 64 + lane) * 8]);
                bf16x8 w2 = as_bf16x8(*(const u32x4a*)&sw[((14 + nt * 3 + 2) * 64 + lane) * 8]);
                f32x4 b = *(const f32x4a*)&sb[224 + nt * 16 + q4];
                f32x4 aA = __builtin_amdgcn_mfma_f32_16x16x32_bf16(w0, x_embA, b, 0, 0, 0);
                aA = __builtin_amdgcn_mfma_f32_16x16x32_bf16(w1, x_dirA, aA, 0, 0, 0);
                aA = __builtin_amdgcn_mfma_f32_16x16x32_bf16(w2, xfA, aA, 0, 0, 0);
                f32x4 aB = __builtin_amdgcn_mfma_f32_16x16x32_bf16(w0, x_embB, b, 0, 0, 0);
                aB = __builtin_amdgcn_mfma_f32_16x16x32_bf16(w1, x_dirB, aB, 0, 0, 0);
                aB = __builtin_amdgcn_mfma_f32_16x16x32_bf16(w2, xfB, aB, 0, 0, 0);
                SPST(&hA[nt * 16 + q4], aA);
                SPST(&hB[nt * 16 + q4], aB);
            }
        }
        // ---- rgb layer 1: K=64, out 64 ----
        {
            bf16x8 hA0 = as_bf16x8(*(const u32x4a*)&hA[0 + q8]);
            bf16x8 hA1 = as_bf16x8(*(const u32x4a*)&hA[32 + q8]);
            bf16x8 hB0 = as_bf16x8(*(const u32x4a*)&hB[0 + q8]);
            bf16x8 hB1 = as_bf16x8(*(const u32x4a*)&hB[32 + q8]);
#pragma unroll
            for (int nt = 0; nt < 4; ++nt) {
                bf16x8 w0 = as_bf16x8(*(const u32x4a*)&sw[((26 + nt * 2 + 0) * 64 + lane) * 8]);
                bf16x8 w1 = as_bf16x8(*(const u32x4a*)&sw[((26 + nt * 2 + 1) * 64 + lane) * 8]);
                f32x4 b = *(const f32x4a*)&sb[144 + nt * 16 + q4];
                f32x4 aA = __builtin_amdgcn_mfma_f32_16x16x32_bf16(w0, hA0, b, 0, 0, 0);
                aA = __builtin_amdgcn_mfma_f32_16x16x32_bf16(w1, hA1, aA, 0, 0, 0);
                f32x4 aB = __builtin_amdgcn_mfma_f32_16x16x32_bf16(w0, hB0, b, 0, 0, 0);
                aB = __builtin_amdgcn_mfma_f32_16x16x32_bf16(w1, hB1, aB, 0, 0, 0);
                SPST(&hA[nt * 16 + q4], aA);
                SPST(&hB[nt * 16 + q4], aB);
            }
        }
        // ---- rgb layer 2: K=64, outs 0..2 (sigmoid) + epilogue ----
        {
            bf16x8 hA0 = as_bf16x8(*(const u32x4a*)&hA[0 + q8]);
            bf16x8 hA1 = as_bf16x8(*(const u32x4a*)&hA[32 + q8]);
            bf16x8 hB0 = as_bf16x8(*(const u32x4a*)&hB[0 + q8]);
            bf16x8 hB1 = as_bf16x8(*(const u32x4a*)&hB[32 + q8]);
            bf16x8 w0 = as_bf16x8(*(const u32x4a*)&sw[(34 * 64 + lane) * 8]);
            bf16x8 w1 = as_bf16x8(*(const u32x4a*)&sw[(35 * 64 + lane) * 8]);
            f32x4 b = *(const f32x4a*)&sb[208 + q4];
            f32x4 aA = __builtin_amdgcn_mfma_f32_16x16x32_bf16(w0, hA0, b, 0, 0, 0);
            aA = __builtin_amdgcn_mfma_f32_16x16x32_bf16(w1, hA1, aA, 0, 0, 0);
            f32x4 aB = __builtin_amdgcn_mfma_f32_16x16x32_bf16(w0, hB0, b, 0, 0, 0);
            aB = __builtin_amdgcn_mfma_f32_16x16x32_bf16(w1, hB1, aB, 0, 0, 0);
            if (q == 0) {  // lane c holds all channels of its points
                f32x4 oA;
                oA[0] = sigmoid_f(aA[0]);
                oA[1] = sigmoid_f(aA[1]);
                oA[2] = sigmoid_f(aA[2]);
                oA[3] = occA;
                *(f32x4a*)&out[(p0 + c) * 4] = oA;
                out[(long)4 * n + p0 + c] = occA;
                f32x4 oB;
                oB[0] = sigmoid_f(aB[0]);
                oB[1] = sigmoid_f(aB[1]);
                oB[2] = sigmoid_f(aB[2]);
                oB[3] = occB;
                *(f32x4a*)&out[(p0 + 16 + c) * 4] = oB;
                out[(long)4 * n + p0 + 16 + c] = occB;
            }
        }
    }
}

extern "C" void kernel_launch(void* const* d_in, const int* in_sizes, int n_in,
                              void* d_out, int out_size, void* d_ws, size_t ws_size,
                              hipStream_t stream) {
    const int n = in_sizes[0] / 32;  // N = 524288
    float*  wsf = (float*)d_ws;
    ushort* wsw = (ushort*)((char*)d_ws + 1152);
    prep_weights<<<8, 256, 0, stream>>>(
        (const float*)d_in[2], (const float*)d_in[3],
        (const float*)d_in[4], (const float*)d_in[5],
        (const float*)d_in[6], (const float*)d_in[7],
        (const float*)d_in[8], (const float*)d_in[9],
        (const float*)d_in[10], (const float*)d_in[11],
        (const float*)d_in[12], (const float*)d_in[13],
        (const float*)d_in[14], (const int*)d_in[15],
        wsf, wsw);
    net_mfma<<<n / 1024, 512, 0, stream>>>(
        (const float*)d_in[0], (const float*)d_in[1],
        wsf, wsw, (float*)d_out, n);
}